// Round 3
// baseline (327.392 us; speedup 1.0000x reference)
//
#include <hip/hip_runtime.h>

// CSR SpMM, sum aggregation: out[i] = sum_{j in [rowptr[i], rowptr[i+1])} x[col[j]]
// x: [N=50000, D=128] f32, rowptr: [N+1] i32, col: [E=1.6M] i32, out: [N, D] f32.
//
// Two-lever design:
//  1) XCD feature partition: D=128 split into 8 chunks of 16 floats (4 lanes
//     x float4). Block b handles chunk (b % 8); dispatch round-robins blocks
//     over the 8 XCDs, so each XCD's 4 MiB L2 caches only a 3.2 MB x-slice
//     -> gathers hit local L2. col/out are nontemporal to protect the slice.
//  2) Balanced edges (merge-path style): each 4-lane group owns a fixed
//     256-edge range. Binary-search the starting row; rows fully inside the
//     range -> direct store; boundary rows -> atomicAdd onto zeroed out.
//     Every group does identical gather work -> no row-skew divergence.

#define CHUNKS 8
#define EPG 256              // edges per 4-lane group
#define GROUPS_PER_BLOCK 64  // 256 threads / 4 lanes

typedef float f32x4 __attribute__((ext_vector_type(4)));

__global__ __launch_bounds__(256) void zero_out_kernel(float* __restrict__ out, int n4) {
    f32x4* o = (f32x4*)out;
    const f32x4 z = {0.f, 0.f, 0.f, 0.f};
    for (int i = blockIdx.x * 256 + threadIdx.x; i < n4; i += gridDim.x * 256)
        o[i] = z;
}

__global__ __launch_bounds__(256) void spmm_balanced_kernel(
    const f32x4* __restrict__ x4,      // [N][32] float4
    const int*   __restrict__ rowptr,  // [N+1]
    const int*   __restrict__ col,     // [E]
    float*       __restrict__ out,     // [N][128]
    int n_nodes, int n_edges)
{
    const int lane  = threadIdx.x & 3;                 // float4 slot in chunk
    const int grp   = threadIdx.x >> 2;                // group in block (0..63)
    const int chunk = blockIdx.x % CHUNKS;             // XCD-bound feature chunk
    const int eblk  = blockIdx.x / CHUNKS;
    const int gid   = eblk * GROUPS_PER_BLOCK + grp;   // group id within chunk
    const int a     = gid * EPG;
    if (a >= n_edges) return;
    const int b = min(a + EPG, n_edges);

    const int fbase = chunk * 4 + lane;                // float4 index in row (0..31)
    const f32x4* xb = x4 + fbase;

    // Binary search: last r with rowptr[r] <= a  (row containing edge a).
    int lo = 0, hi = n_nodes - 1;
    while (lo < hi) {
        const int mid = (lo + hi + 1) >> 1;
        if (rowptr[mid] <= a) lo = mid; else hi = mid - 1;
    }
    int r  = lo;
    int rs = rowptr[r];      // current row's true start

    int j = a;
    f32x4 acc = {0.f, 0.f, 0.f, 0.f};
    while (j < b) {
        const int re  = rowptr[r + 1];   // current row's true end
        const int e   = (re < b) ? re : b;
        const int seg = j;
        // 8x unrolled gathers: 8 independent 16B loads per lane in flight.
        for (; j + 8 <= e; j += 8) {
            const int c0 = __builtin_nontemporal_load(col + j + 0);
            const int c1 = __builtin_nontemporal_load(col + j + 1);
            const int c2 = __builtin_nontemporal_load(col + j + 2);
            const int c3 = __builtin_nontemporal_load(col + j + 3);
            const int c4 = __builtin_nontemporal_load(col + j + 4);
            const int c5 = __builtin_nontemporal_load(col + j + 5);
            const int c6 = __builtin_nontemporal_load(col + j + 6);
            const int c7 = __builtin_nontemporal_load(col + j + 7);
            f32x4 v0 = xb[(size_t)c0 * 32];
            f32x4 v1 = xb[(size_t)c1 * 32];
            f32x4 v2 = xb[(size_t)c2 * 32];
            f32x4 v3 = xb[(size_t)c3 * 32];
            f32x4 v4 = xb[(size_t)c4 * 32];
            f32x4 v5 = xb[(size_t)c5 * 32];
            f32x4 v6 = xb[(size_t)c6 * 32];
            f32x4 v7 = xb[(size_t)c7 * 32];
            acc += v0; acc += v1; acc += v2; acc += v3;
            acc += v4; acc += v5; acc += v6; acc += v7;
        }
        for (; j < e; ++j) {
            const int c = __builtin_nontemporal_load(col + j);
            acc += xb[(size_t)c * 32];
        }

        if (e == re) {
            // Row r's edges end inside our range: emit its partial/total.
            if (j > seg) {
                const bool owner = (rs >= a);   // row started in-range too -> exclusive
                float* dst = out + ((size_t)r * 32 + fbase) * 4;
                if (owner) {
                    __builtin_nontemporal_store(acc, (f32x4*)dst);
                } else {
                    atomicAdd(dst + 0, acc.x);
                    atomicAdd(dst + 1, acc.y);
                    atomicAdd(dst + 2, acc.z);
                    atomicAdd(dst + 3, acc.w);
                }
                acc = (f32x4){0.f, 0.f, 0.f, 0.f};
            }
            rs = re;
            ++r;
        } else {
            // e == b < re: row continues past our range -> boundary partial.
            if (j > seg) {
                float* dst = out + ((size_t)r * 32 + fbase) * 4;
                atomicAdd(dst + 0, acc.x);
                atomicAdd(dst + 1, acc.y);
                atomicAdd(dst + 2, acc.z);
                atomicAdd(dst + 3, acc.w);
            }
            break;
        }
    }
}

extern "C" void kernel_launch(void* const* d_in, const int* in_sizes, int n_in,
                              void* d_out, int out_size, void* d_ws, size_t ws_size,
                              hipStream_t stream) {
    const float* x      = (const float*)d_in[0];
    const int*   rowptr = (const int*)d_in[1];
    const int*   col    = (const int*)d_in[2];
    float*       out    = (float*)d_out;

    const int n_nodes = in_sizes[1] - 1;
    const int n_edges = in_sizes[2];

    // Zero output (boundary rows accumulate via atomicAdd).
    zero_out_kernel<<<2048, 256, 0, stream>>>(out, out_size / 4);

    const int groups_per_chunk = (n_edges + EPG - 1) / EPG;
    const int blocks_per_chunk = (groups_per_chunk + GROUPS_PER_BLOCK - 1) / GROUPS_PER_BLOCK;
    const int blocks = blocks_per_chunk * CHUNKS;
    spmm_balanced_kernel<<<blocks, 256, 0, stream>>>(
        (const f32x4*)x, rowptr, col, out, n_nodes, n_edges);
}

// Round 4
// 80.772 us; speedup vs baseline: 4.0533x; 4.0533x over previous
//
#include <hip/hip_runtime.h>

// CSR SpMM, sum aggregation: out[i] = sum_{j in [rowptr[i], rowptr[i+1])} x[col[j]]
// x: [N=50000, D=128] f32, rowptr: [N+1] i32, col: [E=1.6M] i32, out: [N, D] f32.
//
// Strategy: the gather stream (1.6M x 512B = 819 MB from a 25.6 MB working
// set) is bound on the L2-miss/L3 path (~3.2 TB/s observed, round 1). Halve
// it: one streaming pass converts x to bf16 (RNE) in d_ws (12.8 MB working
// set, 256B rows), then the gather kernel reads bf16 and accumulates in f32.
// Geometry: 16 lanes x 16B (8 bf16) per row, 16 rows per 256-thread block,
// edge loop 8x unrolled -> 8 independent 16B gathers in flight per lane.

typedef float f32x4 __attribute__((ext_vector_type(4)));
typedef unsigned int u32;

// ---- x (f32) -> bf16-packed (u32 holds feats 2k,2k+1), RNE rounding ----
__global__ __launch_bounds__(256) void cvt_bf16_kernel(
    const float2* __restrict__ x2, u32* __restrict__ xb, int npairs)
{
    for (int i = blockIdx.x * 256 + threadIdx.x; i < npairs; i += gridDim.x * 256) {
        const float2 f = x2[i];
        u32 a = __float_as_uint(f.x);
        a = (a + 0x7FFFu + ((a >> 16) & 1u)) >> 16;
        u32 b = __float_as_uint(f.y);
        b = (b + 0x7FFFu + ((b >> 16) & 1u)) & 0xFFFF0000u;
        xb[i] = a | b;
    }
}

__device__ __forceinline__ void addv(float* acc, const uint4 v) {
    acc[0] += __uint_as_float(v.x << 16);
    acc[1] += __uint_as_float(v.x & 0xFFFF0000u);
    acc[2] += __uint_as_float(v.y << 16);
    acc[3] += __uint_as_float(v.y & 0xFFFF0000u);
    acc[4] += __uint_as_float(v.z << 16);
    acc[5] += __uint_as_float(v.z & 0xFFFF0000u);
    acc[6] += __uint_as_float(v.w << 16);
    acc[7] += __uint_as_float(v.w & 0xFFFF0000u);
}

// ---- gather kernel over bf16 x: 16 lanes per row, 16 rows per block ----
__global__ __launch_bounds__(256) void spmm_bf16_kernel(
    const uint4* __restrict__ xb,      // [N][16] (16B = 8 bf16 feats each)
    const int*   __restrict__ rowptr,
    const int*   __restrict__ col,
    float*       __restrict__ out,     // [N][128] f32
    int n_nodes)
{
    const int lane16 = threadIdx.x & 15;   // which 8-feat slice
    const int grp    = threadIdx.x >> 4;   // row within block (0..15)
    const int row    = blockIdx.x * 16 + grp;
    if (row >= n_nodes) return;

    const uint4* xbl = xb + lane16;
    const int r1 = rowptr[row + 1];
    int j = rowptr[row];

    float acc[8] = {0.f, 0.f, 0.f, 0.f, 0.f, 0.f, 0.f, 0.f};

    for (; j + 8 <= r1; j += 8) {
        const int c0 = col[j + 0];
        const int c1 = col[j + 1];
        const int c2 = col[j + 2];
        const int c3 = col[j + 3];
        const int c4 = col[j + 4];
        const int c5 = col[j + 5];
        const int c6 = col[j + 6];
        const int c7 = col[j + 7];
        const uint4 v0 = xbl[(size_t)c0 * 16];
        const uint4 v1 = xbl[(size_t)c1 * 16];
        const uint4 v2 = xbl[(size_t)c2 * 16];
        const uint4 v3 = xbl[(size_t)c3 * 16];
        const uint4 v4 = xbl[(size_t)c4 * 16];
        const uint4 v5 = xbl[(size_t)c5 * 16];
        const uint4 v6 = xbl[(size_t)c6 * 16];
        const uint4 v7 = xbl[(size_t)c7 * 16];
        addv(acc, v0); addv(acc, v1); addv(acc, v2); addv(acc, v3);
        addv(acc, v4); addv(acc, v5); addv(acc, v6); addv(acc, v7);
    }
    for (; j < r1; ++j) {
        const uint4 v = xbl[(size_t)col[j] * 16];
        addv(acc, v);
    }

    float* dst = out + (size_t)row * 128 + lane16 * 8;
    ((f32x4*)dst)[0] = (f32x4){acc[0], acc[1], acc[2], acc[3]};
    ((f32x4*)dst)[1] = (f32x4){acc[4], acc[5], acc[6], acc[7]};
}

// ---- fallback: round-1 fp32 kernel (if ws too small for bf16 copy) ----
__global__ __launch_bounds__(256) void spmm_f32_kernel(
    const f32x4* __restrict__ x4,
    const int*   __restrict__ rowptr,
    const int*   __restrict__ col,
    f32x4*       __restrict__ out4,
    int n_nodes)
{
    const int lane = threadIdx.x & 31;
    const int grp  = threadIdx.x >> 5;
    const int row  = blockIdx.x * 8 + grp;
    if (row >= n_nodes) return;

    const int r1 = rowptr[row + 1];
    int j = rowptr[row];
    f32x4 acc = {0.f, 0.f, 0.f, 0.f};
    for (; j + 4 <= r1; j += 4) {
        const int c0 = col[j + 0];
        const int c1 = col[j + 1];
        const int c2 = col[j + 2];
        const int c3 = col[j + 3];
        f32x4 a = x4[(size_t)c0 * 32 + lane];
        f32x4 b = x4[(size_t)c1 * 32 + lane];
        f32x4 c = x4[(size_t)c2 * 32 + lane];
        f32x4 d = x4[(size_t)c3 * 32 + lane];
        acc += a; acc += b; acc += c; acc += d;
    }
    for (; j < r1; ++j) acc += x4[(size_t)col[j] * 32 + lane];
    out4[(size_t)row * 32 + lane] = acc;
}

extern "C" void kernel_launch(void* const* d_in, const int* in_sizes, int n_in,
                              void* d_out, int out_size, void* d_ws, size_t ws_size,
                              hipStream_t stream) {
    const float* x      = (const float*)d_in[0];
    const int*   rowptr = (const int*)d_in[1];
    const int*   col    = (const int*)d_in[2];
    float*       out    = (float*)d_out;

    const int n_nodes = in_sizes[1] - 1;
    const int n_feats = in_sizes[0] / (in_sizes[1] - 1);   // 128
    const size_t xb_bytes = (size_t)in_sizes[0] * 2;       // bf16 copy of x

    if (ws_size >= xb_bytes && n_feats == 128) {
        u32* xb = (u32*)d_ws;
        const int npairs = in_sizes[0] / 2;
        cvt_bf16_kernel<<<2048, 256, 0, stream>>>((const float2*)x, xb, npairs);
        const int blocks = (n_nodes + 15) / 16;
        spmm_bf16_kernel<<<blocks, 256, 0, stream>>>(
            (const uint4*)xb, rowptr, col, out, n_nodes);
    } else {
        const int blocks = (n_nodes + 7) / 8;
        spmm_f32_kernel<<<blocks, 256, 0, stream>>>(
            (const f32x4*)x, rowptr, col, (f32x4*)out, n_nodes);
    }
}

// Round 5
// 66.915 us; speedup vs baseline: 4.8927x; 1.2071x over previous
//
#include <hip/hip_runtime.h>

// CSR SpMM, sum aggregation: out[i] = sum_{j in [rowptr[i], rowptr[i+1])} x[col[j]]
// x: [N=50000, D=128] f32, rowptr: [N+1] i32, col: [E=1.6M] i32, out: [N, D] f32.
//
// Pass 1: stream-convert x to bf16 (RNE) in d_ws -> 12.8 MB working set.
// Pass 2: one ROW PER WAVE gather. 64 lanes = 4 edges in flight per
// instruction (16 lanes x 16B = one 256B bf16 row per edge), 4x unrolled
// -> 16 edges/iter, 4 loads in flight per lane. 50000 waves => ~195
// sequential waves/CU: full occupancy, row-length skew self-averages.
// End-of-row reduction: shfl_xor over the 4 edge slots (16, 32).

typedef float f32x4 __attribute__((ext_vector_type(4)));
typedef unsigned int u32;

// ---- x (f32) -> bf16-packed (u32 holds feats 2k,2k+1), RNE rounding ----
__global__ __launch_bounds__(256) void cvt_bf16_kernel(
    const float2* __restrict__ x2, u32* __restrict__ xb, int npairs)
{
    for (int i = blockIdx.x * 256 + threadIdx.x; i < npairs; i += gridDim.x * 256) {
        const float2 f = x2[i];
        u32 a = __float_as_uint(f.x);
        a = (a + 0x7FFFu + ((a >> 16) & 1u)) >> 16;
        u32 b = __float_as_uint(f.y);
        b = (b + 0x7FFFu + ((b >> 16) & 1u)) & 0xFFFF0000u;
        xb[i] = a | b;
    }
}

__device__ __forceinline__ void addv(float* acc, const uint4 v) {
    acc[0] += __uint_as_float(v.x << 16);
    acc[1] += __uint_as_float(v.x & 0xFFFF0000u);
    acc[2] += __uint_as_float(v.y << 16);
    acc[3] += __uint_as_float(v.y & 0xFFFF0000u);
    acc[4] += __uint_as_float(v.z << 16);
    acc[5] += __uint_as_float(v.z & 0xFFFF0000u);
    acc[6] += __uint_as_float(v.w << 16);
    acc[7] += __uint_as_float(v.w & 0xFFFF0000u);
}

// ---- one row per wave over bf16 x ----
__global__ __launch_bounds__(256) void spmm_rowwave_kernel(
    const uint4* __restrict__ xb,      // [N][16] : 16 x 16B = 256B bf16 row
    const int*   __restrict__ rowptr,
    const int*   __restrict__ col,
    float*       __restrict__ out,     // [N][128] f32
    int n_nodes)
{
    const int wave = threadIdx.x >> 6;       // 0..3 row within block
    const int lane = threadIdx.x & 63;
    const int sub  = lane >> 4;              // 0..3 edge slot
    const int l16  = lane & 15;              // which 16B slice of the row
    const int row  = blockIdx.x * 4 + wave;
    if (row >= n_nodes) return;

    const uint4* xbl = xb + l16;
    const int r0 = rowptr[row];
    const int r1 = rowptr[row + 1];

    float acc[8] = {0.f, 0.f, 0.f, 0.f, 0.f, 0.f, 0.f, 0.f};

    int j = r0;
    // Main: 16 edges per iteration (4 per edge slot), 4 loads in flight/lane.
    for (; j + 16 <= r1; j += 16) {
        const int c0 = __builtin_nontemporal_load(col + j + sub + 0);
        const int c1 = __builtin_nontemporal_load(col + j + sub + 4);
        const int c2 = __builtin_nontemporal_load(col + j + sub + 8);
        const int c3 = __builtin_nontemporal_load(col + j + sub + 12);
        const uint4 v0 = xbl[(size_t)c0 * 16];
        const uint4 v1 = xbl[(size_t)c1 * 16];
        const uint4 v2 = xbl[(size_t)c2 * 16];
        const uint4 v3 = xbl[(size_t)c3 * 16];
        addv(acc, v0); addv(acc, v1); addv(acc, v2); addv(acc, v3);
    }
    // Mid: 4 edges per iteration.
    for (; j + 4 <= r1; j += 4) {
        const int c = __builtin_nontemporal_load(col + j + sub);
        addv(acc, xbl[(size_t)c * 16]);
    }
    // Tail: < 4 edges, predicated per slot.
    if (j + sub < r1) {
        const int c = __builtin_nontemporal_load(col + j + sub);
        addv(acc, xbl[(size_t)c * 16]);
    }

    // Reduce the 4 edge slots (lanes l16, l16+16, l16+32, l16+48).
    #pragma unroll
    for (int k = 0; k < 8; ++k) {
        acc[k] += __shfl_xor(acc[k], 16, 64);
        acc[k] += __shfl_xor(acc[k], 32, 64);
    }

    if (sub == 0) {
        float* dst = out + (size_t)row * 128 + l16 * 8;
        __builtin_nontemporal_store((f32x4){acc[0], acc[1], acc[2], acc[3]}, (f32x4*)dst);
        __builtin_nontemporal_store((f32x4){acc[4], acc[5], acc[6], acc[7]}, (f32x4*)(dst + 4));
    }
}

// ---- fallback: fp32 row-per-wave (if ws too small for bf16 copy) ----
__global__ __launch_bounds__(256) void spmm_f32_kernel(
    const f32x4* __restrict__ x4,
    const int*   __restrict__ rowptr,
    const int*   __restrict__ col,
    f32x4*       __restrict__ out4,
    int n_nodes)
{
    const int lane = threadIdx.x & 31;
    const int grp  = threadIdx.x >> 5;
    const int row  = blockIdx.x * 8 + grp;
    if (row >= n_nodes) return;

    const int r1 = rowptr[row + 1];
    int j = rowptr[row];
    f32x4 acc = {0.f, 0.f, 0.f, 0.f};
    for (; j + 4 <= r1; j += 4) {
        const int c0 = col[j + 0];
        const int c1 = col[j + 1];
        const int c2 = col[j + 2];
        const int c3 = col[j + 3];
        f32x4 a = x4[(size_t)c0 * 32 + lane];
        f32x4 b = x4[(size_t)c1 * 32 + lane];
        f32x4 c = x4[(size_t)c2 * 32 + lane];
        f32x4 d = x4[(size_t)c3 * 32 + lane];
        acc += a; acc += b; acc += c; acc += d;
    }
    for (; j < r1; ++j) acc += x4[(size_t)col[j] * 32 + lane];
    out4[(size_t)row * 32 + lane] = acc;
}

extern "C" void kernel_launch(void* const* d_in, const int* in_sizes, int n_in,
                              void* d_out, int out_size, void* d_ws, size_t ws_size,
                              hipStream_t stream) {
    const float* x      = (const float*)d_in[0];
    const int*   rowptr = (const int*)d_in[1];
    const int*   col    = (const int*)d_in[2];
    float*       out    = (float*)d_out;

    const int n_nodes = in_sizes[1] - 1;
    const int n_feats = (n_nodes > 0) ? in_sizes[0] / n_nodes : 0;   // 128
    const size_t xb_bytes = (size_t)in_sizes[0] * 2;                  // bf16 copy

    if (ws_size >= xb_bytes && n_feats == 128) {
        u32* xb = (u32*)d_ws;
        const int npairs = in_sizes[0] / 2;
        cvt_bf16_kernel<<<2048, 256, 0, stream>>>((const float2*)x, xb, npairs);
        const int blocks = (n_nodes + 3) / 4;
        spmm_rowwave_kernel<<<blocks, 256, 0, stream>>>(
            (const uint4*)xb, rowptr, col, out, n_nodes);
    } else {
        const int blocks = (n_nodes + 7) / 8;
        spmm_f32_kernel<<<blocks, 256, 0, stream>>>(
            (const f32x4*)x, rowptr, col, (f32x4*)out, n_nodes);
    }
}